// Round 8
// baseline (289.380 us; speedup 1.0000x reference)
//
#include <hip/hip_runtime.h>
#include <hip/hip_bf16.h>

#define NN 10000
#define KK 32
#define DDIRIN 10
#define DDIR 64
#define DD 128          // D_DIST == D_DIST_IN == D_ATOM == 128

#define GEMM_BLOCKS 768   // 3 blocks/CU x 256 CUs, persistent
#define SEG_BLOCKS  (NN / 4)

typedef short bf16x8 __attribute__((ext_vector_type(8)));
typedef float f32x4  __attribute__((ext_vector_type(4)));
typedef float f32x2  __attribute__((ext_vector_type(2)));

__device__ __forceinline__ float silu_f(float x) { return x / (1.0f + __expf(-x)); }

// packed f32x2 -> bf16x2 (RNE) -> raw shorts
__device__ __forceinline__ ushort2 pk_bf16(float a, float b) {
    __hip_bfloat162 h = __float22bfloat162_rn(float2{a, b});
    union { __hip_bfloat162 h; ushort2 u; } v; v.h = h;
    return v.u;
}

// ---- Single heterogeneous kernel ----
// blocks [0, GEMM_BLOCKS): persistent software-pipelined MFMA GEMM, cols 0..128
//   (R7 structure verbatim; bfrag built in-block from dW -> no prep kernel).
// blocks [GEMM_BLOCKS, +SEG_BLOCKS): per-wave seg reduction, cols 128..512
//   (register-only ctz+shfl walk, recompute dir MLPs — proven in R1/R3/R4).
// The two halves write disjoint output columns and run concurrently on the CUs;
// seg + prep time hides under the gemm's latency-bound edist stream.
__global__ __launch_bounds__(256, 3) void mega_kernel(
    const int*   __restrict__ an,      // [N]
    const float* __restrict__ nde,     // [N,10]
    const float* __restrict__ edist,   // [N,32,128]
    const int*   __restrict__ nl,      // [N,32]
    const int*   __restrict__ nmask,   // [N,32]
    const float* __restrict__ semb,    // [100,128]
    const float* __restrict__ temb,    // [100,128]
    const float* __restrict__ sW, const float* __restrict__ sb,
    const float* __restrict__ tW, const float* __restrict__ tb,
    const float* __restrict__ dW,      // [128,128]
    const float* __restrict__ db,      // [128]
    float* __restrict__ out)           // [N,512]
{
    const int tid  = threadIdx.x;
    const int wid  = tid >> 6;
    const int lane = tid & 63;

    __shared__ __align__(16) short s_E[64 * 128];   // 16 KB (gemm branch only)

    if (blockIdx.x < GEMM_BLOCKS) {
        // ================= GEMM branch =================
        const int l15  = lane & 15;
        const int quad = lane >> 4;

        const int NT     = NN / 2;        // 5000 2-node tiles
        const int stride = GEMM_BLOCKS;
        int tile = blockIdx.x;

        // ---- Prologue: issue first tile's loads BEFORE bfrag (overlap latency) ----
        f32x4 va[4], vb[4];
        int   mval;
        {
            const f32x4* E4 = reinterpret_cast<const f32x4*>(edist) + (size_t)tile * 2048;
#pragma unroll
            for (int i = 0; i < 4; ++i) {
                int f0 = 2 * tid + 512 * i;
                va[i] = E4[f0];
                vb[i] = E4[f0 + 1];
            }
            mval = nmask[tile * 64 + lane];   // lane <-> edge row of this tile
        }

        // ---- B fragments: built once per persistent block from dW ----
        bf16x8 bfrag[2][4];
        float  bias[2];
#pragma unroll
        for (int c2 = 0; c2 < 2; ++c2) {
            int ncol = (2 * wid + c2) * 16 + l15;
            bias[c2] = db[ncol];
#pragma unroll
            for (int t = 0; t < 4; ++t) {
                bf16x8 v;
#pragma unroll
                for (int j2 = 0; j2 < 4; ++j2) {
                    int k0 = t * 32 + quad * 8 + 2 * j2;
                    ushort2 u = pk_bf16(dW[k0 * DD + ncol], dW[(k0 + 1) * DD + ncol]);
                    v[2 * j2]     = (short)u.x;
                    v[2 * j2 + 1] = (short)u.y;
                }
                bfrag[c2][t] = v;
            }
        }

        while (true) {
            const unsigned long long bits = __ballot(mval != 0);
            const float cnt0 = (float)__popcll(bits & 0xffffffffull);
            const float cnt1 = (float)__popcll(bits >> 32);
            const int   n0   = tile * 2;

            // ---- cvt f32->bf16, mask-zero, swizzled ds_write ----
#pragma unroll
            for (int i = 0; i < 4; ++i) {
                int row = (tid >> 4) + 16 * i;
                f32x4 a = va[i], b = vb[i];
                ushort2 u0 = pk_bf16(a[0], a[1]), u1 = pk_bf16(a[2], a[3]);
                ushort2 u2 = pk_bf16(b[0], b[1]), u3 = pk_bf16(b[2], b[3]);
                bf16x8 v;
                v[0] = (short)u0.x; v[1] = (short)u0.y; v[2] = (short)u1.x; v[3] = (short)u1.y;
                v[4] = (short)u2.x; v[5] = (short)u2.y; v[6] = (short)u3.x; v[7] = (short)u3.y;
                bf16x8 z;
#pragma unroll
                for (int q = 0; q < 8; ++q) z[q] = 0;
                v = ((bits >> row) & 1ull) ? v : z;
                int kb = tid & 15;
                int sw = kb ^ (row & 7);
                *reinterpret_cast<bf16x8*>(&s_E[row * 128 + sw * 8]) = v;
            }
            __syncthreads();

            // ---- Prefetch NEXT tile (in flight during MFMA + epilogue) ----
            const int  ntile = tile + stride;
            const bool more  = (ntile < NT);
            if (more) {
                const f32x4* E4n = reinterpret_cast<const f32x4*>(edist) + (size_t)ntile * 2048;
#pragma unroll
                for (int i = 0; i < 4; ++i) {
                    int f0 = 2 * tid + 512 * i;
                    va[i] = E4n[f0];
                    vb[i] = E4n[f0 + 1];
                }
                mval = nmask[ntile * 64 + lane];
            }

            // ---- MFMA: C[64 rows x 128 cols]; wave owns 32 cols, 4 row-tiles ----
            f32x4 acc[4][2];
#pragma unroll
            for (int rt = 0; rt < 4; ++rt)
#pragma unroll
                for (int c2 = 0; c2 < 2; ++c2)
#pragma unroll
                    for (int g = 0; g < 4; ++g) acc[rt][c2][g] = 0.0f;

#pragma unroll
            for (int rt = 0; rt < 4; ++rt) {
                bf16x8 af[4];
                int r = rt * 16 + l15;
#pragma unroll
                for (int t = 0; t < 4; ++t) {
                    int kb = (4 * t + quad) ^ (l15 & 7);
                    af[t] = *reinterpret_cast<const bf16x8*>(&s_E[r * 128 + kb * 8]);
                }
#pragma unroll
                for (int t = 0; t < 4; ++t) {
                    acc[rt][0] = __builtin_amdgcn_mfma_f32_16x16x32_bf16(af[t], bfrag[0][t], acc[rt][0], 0, 0, 0);
                    acc[rt][1] = __builtin_amdgcn_mfma_f32_16x16x32_bf16(af[t], bfrag[1][t], acc[rt][1], 0, 0, 0);
                }
            }

            // ---- Epilogue. D layout: col=l15, row=quad*4+g (+16*rt). ----
#pragma unroll
            for (int c2 = 0; c2 < 2; ++c2) {
                float sbv = silu_f(bias[c2]);
#pragma unroll
                for (int nd = 0; nd < 2; ++nd) {
                    float p = 0.0f;
#pragma unroll
                    for (int h = 0; h < 2; ++h) {
                        int rt = 2 * nd + h;
#pragma unroll
                        for (int g = 0; g < 4; ++g)
                            p += silu_f(acc[rt][c2][g] + bias[c2]);
                    }
                    p += __shfl_xor(p, 16);
                    p += __shfl_xor(p, 32);
                    if (quad == nd) {
                        float c = (nd == 0) ? cnt0 : cnt1;
                        float val = (p - (32.0f - c) * sbv) / (c + 1e-5f);
                        out[(size_t)(n0 + nd) * 512 + (2 * wid + c2) * 16 + l15] = val;
                    }
                }
            }

            if (!more) break;        // uniform across block
            __syncthreads();         // protect s_E before next overwrite
            tile = ntile;
        }
        return;
    }

    // ================= SEG branch (cols 128..512), one wave per node =================
    {
        const int n = (blockIdx.x - GEMM_BLOCKS) * 4 + wid;

        int j = 0, aj = 0; bool act = false;
        if (lane < KK) {
            j   = nl[n * KK + lane];
            act = (nmask[n * KK + lane] != 0);
        }
        unsigned long long bits = __ballot(act);
        int cnt = (int)__popcll(bits);
        if (act) aj = an[j];

        const float invv  = 1.0f / ((float)cnt + 1e-5f);
        const float scale = (float)cnt * invv;
        float* outn = out + (size_t)n * 512;

        // sender dir (128..192) + sender atom (192..320): ctz+shfl walk, no LDS
        {
            float sw_r[DDIRIN];
#pragma unroll
            for (int q = 0; q < DDIRIN; ++q) sw_r[q] = sW[q * DDIR + lane];
            const float sbv = sb[lane];

            float sdir = 0.0f, sa0 = 0.0f, sa1 = 0.0f;
            unsigned long long rem = bits;
#pragma unroll 4
            for (int i = 0; i < cnt; ++i) {
                int src = __builtin_ctzll(rem); rem &= rem - 1ull;
                int jj = __shfl(j, src);
                int ja = __shfl(aj, src);
                const f32x2* x2 = reinterpret_cast<const f32x2*>(nde + (size_t)jj * DDIRIN);
                float a = sbv;
#pragma unroll
                for (int q = 0; q < 5; ++q) {
                    f32x2 xv = x2[q];
                    a = fmaf(xv[0], sw_r[2 * q], a);
                    a = fmaf(xv[1], sw_r[2 * q + 1], a);
                }
                sdir += silu_f(a);
                f32x2 e = reinterpret_cast<const f32x2*>(semb + (size_t)ja * DD)[lane];
                sa0 += e[0]; sa1 += e[1];
            }
            outn[128 + lane] = sdir * invv;
            f32x2 sa = {sa0 * invv, sa1 * invv};
            *reinterpret_cast<f32x2*>(&outn[192 + 2 * lane]) = sa;
        }

        // recv dir (320..384)
        {
            const f32x2* x2 = reinterpret_cast<const f32x2*>(nde + (size_t)n * DDIRIN);
            float a = tb[lane];
#pragma unroll
            for (int q = 0; q < 5; ++q) {
                f32x2 xv = x2[q];
                a = fmaf(xv[0], tW[(2 * q) * DDIR + lane], a);
                a = fmaf(xv[1], tW[(2 * q + 1) * DDIR + lane], a);
            }
            outn[320 + lane] = silu_f(a) * scale;
        }

        // recv atom (384..512)
        {
            int ann = an[n];
            f32x2 r = reinterpret_cast<const f32x2*>(temb + (size_t)ann * DD)[lane];
            f32x2 rv = {r[0] * scale, r[1] * scale};
            *reinterpret_cast<f32x2*>(&outn[384 + 2 * lane]) = rv;
        }
    }
}

extern "C" void kernel_launch(void* const* d_in, const int* in_sizes, int n_in,
                              void* d_out, int out_size, void* d_ws, size_t ws_size,
                              hipStream_t stream) {
    const int*   an    = (const int*)  d_in[0];
    const float* nde   = (const float*)d_in[1];
    const float* edist = (const float*)d_in[2];
    const int*   nl    = (const int*)  d_in[3];
    const int*   nmask = (const int*)  d_in[4];
    const float* semb  = (const float*)d_in[5];
    const float* temb  = (const float*)d_in[6];
    const float* sW    = (const float*)d_in[7];
    const float* sb    = (const float*)d_in[8];
    const float* tW    = (const float*)d_in[9];
    const float* tb    = (const float*)d_in[10];
    const float* dW    = (const float*)d_in[11];
    const float* db    = (const float*)d_in[12];
    float* out = (float*)d_out;

    mega_kernel<<<GEMM_BLOCKS + SEG_BLOCKS, 256, 0, stream>>>(
        an, nde, edist, nl, nmask, semb, temb, sW, sb, tW, tb, dW, db, out);
}